// Round 9
// baseline (78.407 us; speedup 1.0000x reference)
//
#include <hip/hip_runtime.h>

// ============================================================================
// ROUND 9 COUNTER PROBE: best-known kernel body repeated REP=4x inside one
// dispatch (opaque pointers defeat cross-iteration CSE). Purpose: push our
// dispatch above the 40us harness fills so it appears in rocprof top-5 with
// full PMC, attributing exec time to VALU / writes / fetch / LDS. Each
// iteration is idempotent -> correctness unaffected. Next round reverts to
// REP=1 and applies the indicated fix.
// ============================================================================

#define NN 1024
#define DD 64
#define NF 11
#define TI 16
#define BT 1024
#define REP 4

__global__ __launch_bounds__(BT, 8) void featuresim_kernel(
    const float* __restrict__ x,
    const int* __restrict__ x_lengths,
    const float* __restrict__ fimp,
    float* __restrict__ out)
{
    const int tid = threadIdx.x;
    const int b   = blockIdx.x >> 6;            // 64 row-groups per batch
    const int i0  = (blockIdx.x & 63) * TI;
    const int len = x_lengths[b];

    __shared__ float partials[TI][BT];    // 64 KiB
    __shared__ float totals[TI];

    const int lane = tid & 63;
    const int wid  = tid >> 6;
    const int j0   = tid;
    const bool valid = j0 < len;

    for (int it = 0; it < REP; ++it) {
        // opaque per-iteration pointers: forces full reload+recompute+restore
        const float* xp = x;
        const float* fp = fimp;
        float*       op = out;
        asm volatile("" : "+s"(xp), "+s"(fp), "+s"(op));

        float fi[NF];
        #pragma unroll
        for (int k = 0; k < NF; ++k) fi[k] = fp[k];

        float fj[NF];
        {
            const float4* p = reinterpret_cast<const float4*>(
                xp + (size_t)(b * NN + j0) * DD);
            float4 a = p[0], c = p[1], d = p[2];
            fj[0] = a.x; fj[1] = a.y; fj[2]  = a.z; fj[3] = a.w;
            fj[4] = c.x; fj[5] = c.y; fj[6]  = c.z; fj[7] = c.w;
            fj[8] = d.x; fj[9] = d.y; fj[10] = d.z;
        }

        float e[TI];

        // ---- phase 1: all 16 rows (q uniform-addr loads), partials write
        #pragma unroll
        for (int r = 0; r < TI; ++r) {
            const float* qp = xp + (size_t)(b * NN + i0 + r) * DD;
            float s = 0.0f;
            #pragma unroll
            for (int k = 0; k < NF; ++k) {
                float d = qp[k] - fj[k];
                s = fmaf(-fabsf(d), fi[k], s);
            }
            float val = (s > -1.0f) ? s : 0.0f;
            float ev  = valid ? __expf(val) : 0.0f;
            e[r] = ev;
            partials[r][tid] = ev;
        }
        __syncthreads();                               // (1) partials ready

        // ---- phase 2: wave w reduces row w via 4x ds_read_b128
        {
            float s = 0.0f;
            #pragma unroll
            for (int m = 0; m < 4; ++m) {
                float4 v4 = *reinterpret_cast<const float4*>(
                    &partials[wid][lane * 4 + 256 * m]);
                s += (v4.x + v4.y) + (v4.z + v4.w);
            }
            #pragma unroll
            for (int off = 32; off >= 1; off >>= 1)
                s += __shfl_xor(s, off, 64);
            if (lane == 0) totals[wid] = s;
        }
        __syncthreads();                               // (2) totals ready

        // ---- phase 3: normalize + coalesced dword stores
        #pragma unroll
        for (int r = 0; r < TI; ++r) {
            const float inv = __builtin_amdgcn_rcpf(totals[r]);
            op[(size_t)(b * NN + i0 + r) * NN + j0] = e[r] * inv;
        }
        // no tail barrier needed: next iter's partials writes are ordered
        // after this iter's phase-2 reads by barrier (2); next iter's totals
        // write is ordered after this iter's phase-3 reads by its barrier (1).
    }
}

extern "C" void kernel_launch(void* const* d_in, const int* in_sizes, int n_in,
                              void* d_out, int out_size, void* d_ws, size_t ws_size,
                              hipStream_t stream) {
    const float* x    = (const float*)d_in[0];
    const int*   xlen = (const int*)d_in[1];
    const float* fimp = (const float*)d_in[2];
    float*       out  = (float*)d_out;

    const int B = in_sizes[1];                  // 8
    dim3 grid(B * (NN / TI));                   // 512 blocks
    dim3 block(BT);
    featuresim_kernel<<<grid, block, 0, stream>>>(x, xlen, fimp, out);
}

// Round 10
// 20.422 us; speedup vs baseline: 3.8394x; 3.8394x over previous
//
#include <hip/hip_runtime.h>

#define NN 1024
#define DD 64
#define NF 11
#define TI 16
#define BT 1024

// Softmax-without-max is exact here: valid scores are in (-1, 0], masked keys
// contribute exactly +0.0, len >= 1 so every row-sum > 0.
//
// R10: the block's key-feature slab (1024 rows x 12 floats, 48KB) is staged
// COALESCED through the partials LDS buffer (reused before phase 1 needs it)
// instead of each thread issuing 3 x dwordx4 at 256B lane-stride (64 cache
// lines per wave-instr, ~192 TA-cycles/wave x 32 waves/CU ~= 2.6us startup
// bubble on the critical path). Staging: ~21 lines/instr, then 3 ds_read_b128.
__global__ __launch_bounds__(BT, 8) void featuresim_kernel(
    const float* __restrict__ x,
    const int* __restrict__ x_lengths,
    const float* __restrict__ fimp,
    float* __restrict__ out)
{
    const int tid = threadIdx.x;
    const int b   = blockIdx.x >> 6;            // 64 row-groups per batch
    const int i0  = (blockIdx.x & 63) * TI;
    const int len = x_lengths[b];

    // feature_importance: uniform -> SGPRs
    float fi[NF];
    #pragma unroll
    for (int k = 0; k < NF; ++k) fi[k] = fimp[k];

    __shared__ float partials[TI][BT];    // 64 KiB; bytes [0,49152) reused as fj stage
    __shared__ float totals[TI];

    // ---- coalesced fj staging: x[b][row][0..11] -> stage[row][12]
    float* stage = &partials[0][0];
    {
        const float* xb = x + (size_t)b * NN * DD;
        #pragma unroll
        for (int i = 0; i < 3; ++i) {
            const int f4  = tid + i * BT;        // 0..3071 float4-slots
            const int row = f4 / 3;
            const int sub = f4 - row * 3;        // 0..2 (16B chunk within 48B row)
            float4 v = *reinterpret_cast<const float4*>(xb + row * DD + sub * 4);
            reinterpret_cast<float4*>(stage)[f4] = v;
        }
    }
    __syncthreads();                      // (A) stage visible (also drains vmcnt)

    // each thread owns key row j = tid: 3x ds_read_b128 (4-way bank alias, cheap)
    float fj[NF];
    {
        const float4* sp = reinterpret_cast<const float4*>(stage + tid * 12);
        float4 a = sp[0], c = sp[1], d = sp[2];
        fj[0] = a.x; fj[1] = a.y; fj[2]  = a.z; fj[3] = a.w;
        fj[4] = c.x; fj[5] = c.y; fj[6]  = c.z; fj[7] = c.w;
        fj[8] = d.x; fj[9] = d.y; fj[10] = d.z;
    }
    const bool valid = tid < len;

    // ---- phase 1: all 16 rows into registers (NO LDS ops before barrier B)
    float e[TI];
    #pragma unroll
    for (int r = 0; r < TI; ++r) {
        const float* qp = x + (size_t)(b * NN + i0 + r) * DD;  // uniform -> s_load
        float s = 0.0f;
        #pragma unroll
        for (int k = 0; k < NF; ++k) {
            float d = qp[k] - fj[k];
            s = fmaf(-fabsf(d), fi[k], s);     // -abs() is a VOP3 input mod
        }
        float val = (s > -1.0f) ? s : 0.0f;
        e[r] = valid ? __expf(val) : 0.0f;
    }
    __syncthreads();                      // (B) all stage reads done; safe to overwrite

    #pragma unroll
    for (int r = 0; r < TI; ++r)
        partials[r][tid] = e[r];
    __syncthreads();                      // (1) partials ready

    // ---- phase 2: wave w reduces row w via 4x ds_read_b128 (conflict-free)
    const int lane = tid & 63;
    const int wid  = tid >> 6;
    {
        float s = 0.0f;
        #pragma unroll
        for (int m = 0; m < 4; ++m) {
            float4 v4 = *reinterpret_cast<const float4*>(
                &partials[wid][lane * 4 + 256 * m]);
            s += (v4.x + v4.y) + (v4.z + v4.w);
        }
        #pragma unroll
        for (int off = 32; off >= 1; off >>= 1)
            s += __shfl_xor(s, off, 64);
        if (lane == 0) totals[wid] = s;
    }
    __syncthreads();                      // (2) totals ready

    // ---- phase 3: normalize + coalesced dword stores (256B/wave/row)
    #pragma unroll
    for (int r = 0; r < TI; ++r) {
        const float inv = __builtin_amdgcn_rcpf(totals[r]);
        out[(size_t)(b * NN + i0 + r) * NN + tid] = e[r] * inv;
    }
}

extern "C" void kernel_launch(void* const* d_in, const int* in_sizes, int n_in,
                              void* d_out, int out_size, void* d_ws, size_t ws_size,
                              hipStream_t stream) {
    const float* x    = (const float*)d_in[0];
    const int*   xlen = (const int*)d_in[1];
    const float* fimp = (const float*)d_in[2];
    float*       out  = (float*)d_out;

    const int B = in_sizes[1];                  // 8
    dim3 grid(B * (NN / TI));                   // 512 blocks = 1 resident generation
    dim3 block(BT);
    featuresim_kernel<<<grid, block, 0, stream>>>(x, xlen, fimp, out);
}